// Round 4
// baseline (243.707 us; speedup 1.0000x reference)
//
#include <hip/hip_runtime.h>
#include <math.h>

// Problem constants
#define NB 32
#define NC 64          // CODE_DIM
#define NK 2048
#define NCODES 1024
#define NVEC (NB*NK)          // 65536 vectors
#define NELEM (NB*NC*NK)      // 4194304 elements
#define NBLK (NVEC/64)        // 1024 blocks for fused kernel

// ws layout (bytes)
#define WS_CODES 0            // int[NVEC]     = 262144 B
#define WS_HIST  262144       // int[NCODES]   = 4096 B
#define WS_CBN32 266240       // float[NCODES] = 4096 B
#define WS_PART  278528       // double[NBLK]  = 8192 B

// numpy pairwise_sum for n=64 (scalar 8-accumulator pattern), on pre-rounded
// squares. Bit-exact vs np.sum(x*x, axis=1) float32 (validated rounds 2-3).
__device__ __forceinline__ float np_sumsq64_row(const float* x) {
    float r[8];
#pragma unroll
    for (int j = 0; j < 8; j++) r[j] = __fmul_rn(x[j], x[j]);
#pragma unroll
    for (int i = 8; i < 64; i += 8)
#pragma unroll
        for (int j = 0; j < 8; j++)
            r[j] = __fadd_rn(r[j], __fmul_rn(x[i + j], x[i + j]));
    float s01 = __fadd_rn(r[0], r[1]), s23 = __fadd_rn(r[2], r[3]);
    float s45 = __fadd_rn(r[4], r[5]), s67 = __fadd_rn(r[6], r[7]);
    return __fadd_rn(__fadd_rn(s01, s23), __fadd_rn(s45, s67));
}

// --- codebook squared norms, numpy-exact fp32 -------------------------------
__global__ void k_cbnorm(const float* __restrict__ cb, float* __restrict__ n32) {
    int j = blockIdx.x * 64 + threadIdx.x;   // 16 x 64 = 1024
    const float* cr = cb + (size_t)j * NC;
    float x[NC];
#pragma unroll
    for (int c = 0; c < NC; c++) x[c] = cr[c];
    n32[j] = np_sumsq64_row(x);
}

// --- fused argmin + quantize ------------------------------------------------
// Block = 256 threads = 4 waves. Wave w: all 64 vectors of the block, code
// partition [w*256, w*256+256). z lives in 64 pinned VGPRs; codebook rows are
// wave-uniform -> SGPR s_loads (no LDS, no VMEM in the hot loop).
// Chains are bit-exact replicas of the validated round-2/3 fp32 sequence.
__launch_bounds__(256, 4)
__global__ void k_argmin_fused(const float* __restrict__ ze,
                               const float* __restrict__ cb,
                               const float* __restrict__ n32,
                               int* __restrict__ codes, int* __restrict__ hist,
                               float* __restrict__ codes_f,
                               float* __restrict__ outq,
                               double* __restrict__ part) {
    const int t = threadIdx.x;
    const int lane = t & 63;                 // vector within block
    const int vec0 = blockIdx.x * 64;        // 64 vectors, one batch b
    const int b = vec0 >> 11;
    const int k0 = vec0 & (NK - 1);
    const float* zp = ze + (size_t)b * NC * NK + (k0 + lane);

    // load z (coalesced: lane = consecutive k) and pin in VGPRs
    float z[NC];
#pragma unroll
    for (int c = 0; c < NC; c++) z[c] = zp[(size_t)c * NK];
#pragma unroll
    for (int c = 0; c < NC; c++) asm volatile("" : "+v"(z[c]));

    // t1 = np.sum(z*z), numpy-exact (redundant across waves, bit-identical)
    float t1 = np_sumsq64_row(z);

    // wave-uniform code partition base (readfirstlane forces SGPR)
    const int wv = __builtin_amdgcn_readfirstlane(t >> 6);  // 0..3
    const int jbase = wv * 256;
    const float* cbp = cb + (size_t)jbase * NC;
    const float* n2p = n32 + jbase;

    float best = 3.0e38f;
    int bidx = 0;
#pragma unroll 2
    for (int j = 0; j < 256; j += 4) {
        const float* cr = cbp + (size_t)j * NC;   // uniform -> s_load
        float a0 = 0.f, a1 = 0.f, a2 = 0.f, a3 = 0.f;
#pragma unroll
        for (int c = 0; c < NC; c++) {
            float zc = z[c];
            a0 = __fmaf_rn(zc, cr[c         ], a0);
            a1 = __fmaf_rn(zc, cr[c +     NC], a1);
            a2 = __fmaf_rn(zc, cr[c + 2 * NC], a2);
            a3 = __fmaf_rn(zc, cr[c + 3 * NC], a3);
        }
        float d0 = __fsub_rn(__fadd_rn(t1, n2p[j + 0]), __fmul_rn(2.f, a0));
        float d1 = __fsub_rn(__fadd_rn(t1, n2p[j + 1]), __fmul_rn(2.f, a1));
        float d2 = __fsub_rn(__fadd_rn(t1, n2p[j + 2]), __fmul_rn(2.f, a2));
        float d3 = __fsub_rn(__fadd_rn(t1, n2p[j + 3]), __fmul_rn(2.f, a3));
        // strict < keeps FIRST minimal index (np.argmin)
        if (d0 < best) { best = d0; bidx = jbase + j + 0; }
        if (d1 < best) { best = d1; bidx = jbase + j + 1; }
        if (d2 < best) { best = d2; bidx = jbase + j + 2; }
        if (d3 < best) { best = d3; bidx = jbase + j + 3; }
    }

    // cross-wave merge: key = (dist_bits<<32)|idx; dist>0 -> bit-monotone;
    // min key == min dist with ties to min idx (numpy first-index rule)
    __shared__ unsigned long long keys[4][64];
    keys[t >> 6][lane] =
        ((unsigned long long)__float_as_uint(best) << 32) | (unsigned int)bidx;
    __syncthreads();

    if (t < 64) {   // wave 0 finishes: merge, outputs, fused quant epilogue
        unsigned long long kmin = keys[0][t];
#pragma unroll
        for (int w = 1; w < 4; w++) {
            unsigned long long kk = keys[w][t];
            if (kk < kmin) kmin = kk;
        }
        int code = (int)(kmin & 0xFFFFFFFFu);
        int n = vec0 + t;
        codes[n] = code;
        codes_f[n] = (float)code;
        atomicAdd(&hist[code], 1);

        // quant epilogue: z is in this thread's regs; gather cb row, write
        // z_q_st = fl(z + fl(q - z)) (validated form), fp64 loss partial
        const float* qrow = cb + (size_t)code * NC;
        float* ob = outq + (size_t)b * NC * NK + (k0 + t);
        double s = 0.0;
#pragma unroll
        for (int c = 0; c < NC; c++) {
            float qv = qrow[c];
            float zev = z[c];
            ob[(size_t)c * NK] = __fadd_rn(zev, __fsub_rn(qv, zev));
            double d = (double)qv - (double)zev;
            s += d * d;
        }
        for (int off = 32; off; off >>= 1) s += __shfl_down(s, off);
        if (t == 0) part[blockIdx.x] = s;
    }
}

// --- final scalars: loss_vq and perplexity ----------------------------------
__launch_bounds__(1024)
__global__ void k_final(const double* __restrict__ part, const int* __restrict__ hist,
                        float* __restrict__ out) {
    int t = threadIdx.x;                         // 1024 threads = NBLK partials
    double vL = part[t];
    double p = (double)hist[t] * (1.0 / (double)NVEC);
    double vE = p * log(p + 1e-10);
    for (int off = 32; off; off >>= 1) {
        vL += __shfl_down(vL, off);
        vE += __shfl_down(vE, off);
    }
    __shared__ double lsL[16], lsE[16];
    int lane = t & 63, wv = t >> 6;
    if (lane == 0) { lsL[wv] = vL; lsE[wv] = vE; }
    __syncthreads();
    if (t == 0) {
        double SL = 0.0, SE = 0.0;
        for (int i = 0; i < 16; i++) { SL += lsL[i]; SE += lsE[i]; }
        double loss_cb = SL / (double)NELEM;     // == loss_commit numerically
        out[NELEM + NVEC]     = (float)(loss_cb + 0.25 * loss_cb);
        out[NELEM + NVEC + 1] = (float)exp(-SE);
    }
}

extern "C" void kernel_launch(void* const* d_in, const int* in_sizes, int n_in,
                              void* d_out, int out_size, void* d_ws, size_t ws_size,
                              hipStream_t stream) {
    const float* ze = (const float*)d_in[0];
    const float* cb = (const float*)d_in[1];
    float* out = (float*)d_out;
    char* ws = (char*)d_ws;

    int*    codes = (int*)(ws + WS_CODES);
    int*    hist  = (int*)(ws + WS_HIST);
    float*  n32   = (float*)(ws + WS_CBN32);
    double* part  = (double*)(ws + WS_PART);

    float* zq      = out;                 // (32, 64, 2048)
    float* codes_f = out + NELEM;         // (32, 2048) as float

    hipMemsetAsync(ws + WS_HIST, 0, NCODES * sizeof(int), stream);
    k_cbnorm<<<16, 64, 0, stream>>>(cb, n32);
    k_argmin_fused<<<NBLK, 256, 0, stream>>>(ze, cb, n32, codes, hist, codes_f,
                                             zq, part);
    k_final<<<1, 1024, 0, stream>>>(part, hist, out);
}